// Round 7
// baseline (54.604 us; speedup 1.0000x reference)
//
#include <hip/hip_runtime.h>

constexpr int B_ = 16;
constexpr int N_ = 500;
constexpr int NC = 10;
constexpr int FM_ = 360;
constexpr int RMAXC = 12;
constexpr long HM_ELEMS = (long)B_ * NC * FM_ * FM_;      // 20,736,000
constexpr long ANNO_OFF = HM_ELEMS;                        // +16*500*8 = 64,000
constexpr long IND_OFF  = ANNO_OFF + (long)B_ * N_ * 8;    // 20,800,000
constexpr long MASK_OFF = IND_OFF + (long)B_ * N_;         // 20,808,000

constexpr int BAND = 15;                      // rows per gather tile
constexpr int NBANDS = FM_ / BAND;            // 24
constexpr int GB_BLKS = B_ * NC * NBANDS;     // 3840

// ws layout: [0,704) int wsStart[16][11]; [1024, 1024+128000) int4 wsPar[16][500]
constexpr size_t WSPAR_OFF = 1024;

struct ObjParams {
    float cx_f, cy_f, sigma;
    int cx, cy, radius;
    bool valid;
};

// Replicates reference float32 op order exactly.
__device__ inline ObjParams compute_params(const float* bx) {
    float x = bx[0], y = bx[1];
    float w = bx[3], l = bx[4];
    ObjParams o;
    float wp = w / 0.075f / 4.0f;
    float lp = l / 0.075f / 4.0f;
    o.cx_f = (x + 54.0f) / 0.075f / 4.0f;   // (x - PCR0), PCR0 = -54.0
    o.cy_f = (y + 54.0f) / 0.075f / 4.0f;
    o.cx = (int)o.cx_f;                      // trunc == .astype(int32)
    o.cy = (int)o.cy_f;
    o.valid = (wp > 0.0f) && (lp > 0.0f) &&
              (o.cx >= 0) && (o.cx < FM_) && (o.cy >= 0) && (o.cy < FM_);
    // gaussian_radius(height=lp, width=wp, min_overlap=0.1)
    float height = lp, width = wp;
    float b1 = height + width;
    float c1 = width * height * 0.9f / 1.1f;
    float r1 = (b1 + sqrtf(b1 * b1 - 4.0f * c1)) / 2.0f;
    float b2 = 2.0f * (height + width);
    float c2 = 0.9f * width * height;
    float r2 = (b2 + sqrtf(b2 * b2 - 16.0f * c2)) / 2.0f;
    float b3 = -0.2f * (height + width);
    float c3 = -0.9f * width * height;
    float r3 = (b3 + sqrtf(b3 * b3 - 1.6f * c3)) / 2.0f;
    float r = fminf(fminf(r1, r2), r3);
    o.radius = max(2, (int)floorf(r));
    // sigma from UNclamped radius (reference); window clamp to R_MAX separate.
    o.sigma = (2.0f * (float)o.radius + 1.0f) / 6.0f;
    return o;
}

// Kernel A: 32 blocks (2 per batch). Stable rank + anno/ind/mask + per-object
// param record written at slot `rank` -> class-bucketed contiguous lists in ws.
__global__ __launch_bounds__(256) void prep_kernel(
        const float* __restrict__ boxes, const int* __restrict__ labels,
        float* __restrict__ out, int* __restrict__ wsStart,
        int4* __restrict__ wsPar) {
    int blk = blockIdx.x;
    int tid = threadIdx.x;
    int b = blk >> 1;
    int half = blk & 1;
    __shared__ int lab[N_];
    for (int k = tid; k < N_; k += 256) lab[k] = labels[b * N_ + k];
    __syncthreads();

    // class-range offsets: wsStart[b][t] = #(cls < t), t = 0..10
    if (half == 0 && tid <= NC) {
        int t = tid, cnt = 0;
        for (int j = 0; j < N_; ++j) cnt += ((lab[j] - 1) < t);
        wsStart[b * (NC + 1) + t] = cnt;
    }

    int i = half * 250 + tid;
    if (tid < 250) {
        int c = lab[i];
        int rank = 0;
        #pragma unroll 8
        for (int j = 0; j < N_; ++j) {
            int lj = lab[j];
            rank += (lj < c) | ((lj == c) & (j < i));
        }
        const float* bx = boxes + (long)(b * N_ + i) * 9;
        ObjParams o = compute_params(bx);

        int4 rec;
        rec.x = o.cx;
        rec.y = o.cy;
        rec.z = o.valid ? min(o.radius, RMAXC) : -1;
        rec.w = __float_as_int(1.0f / (2.0f * (o.sigma * o.sigma)));
        wsPar[b * N_ + rank] = rec;

        float* anno = out + ANNO_OFF + (long)(b * N_ + rank) * 8;
        if (o.valid) {
            float zz = bx[2], w = bx[3], l = bx[4], h = bx[5], rot = bx[8];
            float4 a0 = {o.cx_f - (float)o.cx, o.cy_f - (float)o.cy, zz, logf(w)};
            float4 a1 = {logf(l), logf(h), sinf(rot), cosf(rot)};
            *(float4*)anno = a0;
            *(float4*)(anno + 4) = a1;
            out[IND_OFF + b * N_ + rank]  = (float)(o.cy * FM_ + o.cx);
            out[MASK_OFF + b * N_ + rank] = 1.0f;
        } else {
            float4 z = {0.f, 0.f, 0.f, 0.f};
            *(float4*)anno = z;
            *(float4*)(anno + 4) = z;
            out[IND_OFF + b * N_ + rank]  = 0.0f;
            out[MASK_OFF + b * N_ + rank] = 0.0f;
        }
    }
}

// Kernel B: one block per (batch, class, 15-row band). Scatter gaussians into
// an LDS tile (work = O(covered cells)), then stream the tile out once.
__global__ __launch_bounds__(256) void gather_kernel(
        const int* __restrict__ wsStart, const int4* __restrict__ wsPar,
        float* __restrict__ out) {
    int blk = blockIdx.x;
    int tid = threadIdx.x;
    int b = blk / (NC * NBANDS);
    int rem = blk - b * (NC * NBANDS);
    int c = rem / NBANDS;
    int y0 = (rem - c * NBANDS) * BAND;

    __shared__ int tile[BAND * FM_];        // 21.6 KB, int view for atomicMax
    __shared__ int4 s_rec[N_];              // 8 KB (worst-case all one class)

    int start = wsStart[b * (NC + 1) + c];
    int end   = wsStart[b * (NC + 1) + c + 1];
    int cnt = end - start;
    for (int k = tid; k < cnt; k += 256) s_rec[k] = wsPar[b * N_ + start + k];
    constexpr int NT4 = BAND * FM_ / 4;     // 1350
    int4 z4 = {0, 0, 0, 0};
    for (int k = tid; k < NT4; k += 256) ((int4*)tile)[k] = z4;
    __syncthreads();

    for (int j = 0; j < cnt; ++j) {
        int4 r = s_rec[j];                  // uniform broadcast read
        int re = r.z;
        if (re < 0) continue;               // invalid object
        int cy = r.y;
        int rlo = max(y0, cy - re), rhi = min(y0 + BAND - 1, cy + re);
        if (rlo > rhi) continue;            // window misses band (uniform)
        int cx = r.x;
        float inv = __int_as_float(r.w);
        int wsz = 2 * re + 1;               // <= 25
        int cellsP = (rhi - rlo + 1) << 5;  // rows padded to 32 (no int div)
        for (int cell = tid; cell < cellsP; cell += 256) {
            int row = cell >> 5;
            int dxi = cell & 31;
            if (dxi >= wsz) continue;
            int dx = dxi - re;
            int x = cx + dx;
            if (x < 0 || x >= FM_) continue;
            int dy = rlo + row - cy;
            float g = expf(-(float)(dx * dx + dy * dy) * inv);
            // g >= 0, tile zeroed: int max == float max
            atomicMax(&tile[(rlo - y0 + row) * FM_ + x], __float_as_int(g));
        }
    }
    __syncthreads();

    float4* base4 = (float4*)(out + (((long)(b * NC + c)) * FM_ + y0) * FM_);
    for (int k = tid; k < NT4; k += 256) base4[k] = ((float4*)tile)[k];
}

extern "C" void kernel_launch(void* const* d_in, const int* in_sizes, int n_in,
                              void* d_out, int out_size, void* d_ws, size_t ws_size,
                              hipStream_t stream) {
    const float* boxes = (const float*)d_in[0];
    const int* labels  = (const int*)d_in[1];
    float* out = (float*)d_out;
    int* wsStart = (int*)d_ws;
    int4* wsPar = (int4*)((char*)d_ws + WSPAR_OFF);

    prep_kernel<<<2 * B_, 256, 0, stream>>>(boxes, labels, out, wsStart, wsPar);
    gather_kernel<<<GB_BLKS, 256, 0, stream>>>(wsStart, wsPar, out);
}

// Round 8
// 41.524 us; speedup vs baseline: 1.3150x; 1.3150x over previous
//
#include <hip/hip_runtime.h>

constexpr int B_ = 16;
constexpr int N_ = 500;
constexpr int NC = 10;
constexpr int FM_ = 360;
constexpr int RMAXC = 12;
constexpr long HM_ELEMS = (long)B_ * NC * FM_ * FM_;      // 20,736,000
constexpr long ANNO_OFF = HM_ELEMS;                        // +16*500*8 = 64,000
constexpr long IND_OFF  = ANNO_OFF + (long)B_ * N_ * 8;    // 20,800,000
constexpr long MASK_OFF = IND_OFF + (long)B_ * N_;         // 20,808,000

constexpr int BAND = 15;                      // rows per tile
constexpr int NBANDS = FM_ / BAND;            // 24
constexpr int GB_BLKS = B_ * NC * NBANDS;     // 3840

// ws layout: [0,704) int wsStart[16][11]; [1024, +128000) int4 wsPar[16][500]
constexpr size_t WSPAR_OFF = 1024;

struct ObjParams {
    float cx_f, cy_f, sigma;
    int cx, cy, radius;
    bool valid;
};

// Replicates reference float32 op order exactly.
__device__ inline ObjParams compute_params(const float* bx) {
    float x = bx[0], y = bx[1];
    float w = bx[3], l = bx[4];
    ObjParams o;
    float wp = w / 0.075f / 4.0f;
    float lp = l / 0.075f / 4.0f;
    o.cx_f = (x + 54.0f) / 0.075f / 4.0f;   // (x - PCR0), PCR0 = -54.0
    o.cy_f = (y + 54.0f) / 0.075f / 4.0f;
    o.cx = (int)o.cx_f;                      // trunc == .astype(int32)
    o.cy = (int)o.cy_f;
    o.valid = (wp > 0.0f) && (lp > 0.0f) &&
              (o.cx >= 0) && (o.cx < FM_) && (o.cy >= 0) && (o.cy < FM_);
    // gaussian_radius(height=lp, width=wp, min_overlap=0.1)
    float height = lp, width = wp;
    float b1 = height + width;
    float c1 = width * height * 0.9f / 1.1f;
    float r1 = (b1 + sqrtf(b1 * b1 - 4.0f * c1)) / 2.0f;
    float b2 = 2.0f * (height + width);
    float c2 = 0.9f * width * height;
    float r2 = (b2 + sqrtf(b2 * b2 - 16.0f * c2)) / 2.0f;
    float b3 = -0.2f * (height + width);
    float c3 = -0.9f * width * height;
    float r3 = (b3 + sqrtf(b3 * b3 - 1.6f * c3)) / 2.0f;
    float r = fminf(fminf(r1, r2), r3);
    o.radius = max(2, (int)floorf(r));
    o.sigma = (2.0f * (float)o.radius + 1.0f) / 6.0f;
    return o;
}

// Kernel A: 32 blocks (2 per batch). Stable rank + anno/ind/mask + per-object
// param record at slot `rank` -> class-bucketed contiguous lists in ws.
__global__ __launch_bounds__(256) void prep_kernel(
        const float* __restrict__ boxes, const int* __restrict__ labels,
        float* __restrict__ out, int* __restrict__ wsStart,
        int4* __restrict__ wsPar) {
    int blk = blockIdx.x;
    int tid = threadIdx.x;
    int b = blk >> 1;
    int half = blk & 1;
    __shared__ int lab[N_];
    for (int k = tid; k < N_; k += 256) lab[k] = labels[b * N_ + k];
    __syncthreads();

    if (half == 0 && tid <= NC) {          // wsStart[b][t] = #(cls < t)
        int t = tid, cnt = 0;
        for (int j = 0; j < N_; ++j) cnt += ((lab[j] - 1) < t);
        wsStart[b * (NC + 1) + t] = cnt;
    }

    int i = half * 250 + tid;
    if (tid < 250) {
        int c = lab[i];
        int rank = 0;
        #pragma unroll 8
        for (int j = 0; j < N_; ++j) {
            int lj = lab[j];
            rank += (lj < c) | ((lj == c) & (j < i));
        }
        const float* bx = boxes + (long)(b * N_ + i) * 9;
        ObjParams o = compute_params(bx);

        int4 rec;
        rec.x = o.cx;
        rec.y = o.cy;
        rec.z = o.valid ? min(o.radius, RMAXC) : -1;
        rec.w = __float_as_int(1.0f / (2.0f * (o.sigma * o.sigma)));
        wsPar[b * N_ + rank] = rec;

        float* anno = out + ANNO_OFF + (long)(b * N_ + rank) * 8;
        if (o.valid) {
            float zz = bx[2], w = bx[3], l = bx[4], h = bx[5], rot = bx[8];
            float4 a0 = {o.cx_f - (float)o.cx, o.cy_f - (float)o.cy, zz, logf(w)};
            float4 a1 = {logf(l), logf(h), sinf(rot), cosf(rot)};
            *(float4*)anno = a0;
            *(float4*)(anno + 4) = a1;
            out[IND_OFF + b * N_ + rank]  = (float)(o.cy * FM_ + o.cx);
            out[MASK_OFF + b * N_ + rank] = 1.0f;
        } else {
            float4 z = {0.f, 0.f, 0.f, 0.f};
            *(float4*)anno = z;
            *(float4*)(anno + 4) = z;
            out[IND_OFF + b * N_ + rank]  = 0.0f;
            out[MASK_OFF + b * N_ + rank] = 0.0f;
        }
    }
}

// Kernel B: one block per (batch, class, 15-row band). PARALLEL filter of the
// class's records (coalesced, L2-hot) -> compact ~4 intersecting into LDS ->
// scatter their windows into an LDS tile (atomicMax, 2-way bank = free) ->
// stream tile out once. No zero pass, no global atomics.
__global__ __launch_bounds__(256) void gather_kernel(
        const int* __restrict__ wsStart, const int4* __restrict__ wsPar,
        float* __restrict__ out) {
    int blk = blockIdx.x;
    int tid = threadIdx.x;
    int b = blk / (NC * NBANDS);
    int rem = blk - b * (NC * NBANDS);
    int c = rem / NBANDS;
    int y0 = (rem - c * NBANDS) * BAND;

    __shared__ int tile[BAND * FM_];        // 21.6 KB (int view for atomicMax)
    __shared__ int4 s_list[N_];             // compacted intersecting objects
    __shared__ int s_cnt;

    if (tid == 0) s_cnt = 0;
    // zero tile before sync (independent of filter)
    constexpr int NT4 = BAND * FM_ / 4;     // 1350
    int4 z4 = {0, 0, 0, 0};
    for (int k = tid; k < NT4; k += 256) ((int4*)tile)[k] = z4;
    __syncthreads();

    int start = wsStart[b * (NC + 1) + c];
    int end   = wsStart[b * (NC + 1) + c + 1];
    // parallel filter + compact (order in list irrelevant: max commutes)
    for (int k = start + tid; k < end; k += 256) {
        int4 r = wsPar[b * N_ + k];
        int re = r.z;
        if (re >= 0 && r.y + re >= y0 && r.y - re <= y0 + BAND - 1) {
            int p = atomicAdd(&s_cnt, 1);
            s_list[p] = r;
        }
    }
    __syncthreads();
    int n = s_cnt;

    for (int j = 0; j < n; ++j) {
        int4 r = s_list[j];                 // broadcast read, ~4 iterations
        int cy = r.y, cx = r.x, re = r.z;
        float inv = __int_as_float(r.w);
        int rlo = max(y0, cy - re), rhi = min(y0 + BAND - 1, cy + re);
        int wsz = 2 * re + 1;               // <= 25
        int cellsP = (rhi - rlo + 1) << 5;  // rows padded to 32 lanes
        for (int cell = tid; cell < cellsP; cell += 256) {
            int row = cell >> 5;
            int dxi = cell & 31;
            if (dxi >= wsz) continue;
            int dx = dxi - re;
            int x = cx + dx;
            if (x < 0 || x >= FM_) continue;
            int dy = rlo + row - cy;
            float g = expf(-(float)(dx * dx + dy * dy) * inv);
            atomicMax(&tile[(rlo - y0 + row) * FM_ + x], __float_as_int(g));
        }
    }
    __syncthreads();

    float4* base4 = (float4*)(out + (((long)(b * NC + c)) * FM_ + y0) * FM_);
    for (int k = tid; k < NT4; k += 256) base4[k] = ((float4*)tile)[k];
}

extern "C" void kernel_launch(void* const* d_in, const int* in_sizes, int n_in,
                              void* d_out, int out_size, void* d_ws, size_t ws_size,
                              hipStream_t stream) {
    const float* boxes = (const float*)d_in[0];
    const int* labels  = (const int*)d_in[1];
    float* out = (float*)d_out;
    int* wsStart = (int*)d_ws;
    int4* wsPar = (int4*)((char*)d_ws + WSPAR_OFF);

    prep_kernel<<<2 * B_, 256, 0, stream>>>(boxes, labels, out, wsStart, wsPar);
    gather_kernel<<<GB_BLKS, 256, 0, stream>>>(wsStart, wsPar, out);
}

// Round 9
// 31.366 us; speedup vs baseline: 1.7408x; 1.3238x over previous
//
#include <hip/hip_runtime.h>

constexpr int B_ = 16;
constexpr int N_ = 500;
constexpr int NC = 10;
constexpr int FM_ = 360;
constexpr int RMAXC = 12;
constexpr long HM_ELEMS = (long)B_ * NC * FM_ * FM_;      // 20,736,000
constexpr long ANNO_OFF = HM_ELEMS;                        // +16*500*8 = 64,000
constexpr long IND_OFF  = ANNO_OFF + (long)B_ * N_ * 8;    // 20,800,000
constexpr long MASK_OFF = IND_OFF + (long)B_ * N_;         // 20,808,000

constexpr int PREP_BLKS = 32;     // blocks 0..31: prep (launch first, hide under fill)
constexpr int ZERO_BLKS = 2048;   // blocks 32..2079: zero sweep

struct ObjParams {
    float cx_f, cy_f, sigma;
    int cx, cy, radius;
    bool valid;
};

// Replicates reference float32 op order exactly.
__device__ inline ObjParams compute_params(const float* bx) {
    float x = bx[0], y = bx[1];
    float w = bx[3], l = bx[4];
    ObjParams o;
    float wp = w / 0.075f / 4.0f;
    float lp = l / 0.075f / 4.0f;
    o.cx_f = (x + 54.0f) / 0.075f / 4.0f;   // (x - PCR0), PCR0 = -54.0
    o.cy_f = (y + 54.0f) / 0.075f / 4.0f;
    o.cx = (int)o.cx_f;                      // trunc == .astype(int32)
    o.cy = (int)o.cy_f;
    o.valid = (wp > 0.0f) && (lp > 0.0f) &&
              (o.cx >= 0) && (o.cx < FM_) && (o.cy >= 0) && (o.cy < FM_);
    // gaussian_radius(height=lp, width=wp, min_overlap=0.1)
    float height = lp, width = wp;
    float b1 = height + width;
    float c1 = width * height * 0.9f / 1.1f;
    float r1 = (b1 + sqrtf(b1 * b1 - 4.0f * c1)) / 2.0f;
    float b2 = 2.0f * (height + width);
    float c2 = 0.9f * width * height;
    float r2 = (b2 + sqrtf(b2 * b2 - 16.0f * c2)) / 2.0f;
    float b3 = -0.2f * (height + width);
    float c3 = -0.9f * width * height;
    float r3 = (b3 + sqrtf(b3 * b3 - 1.6f * c3)) / 2.0f;
    float r = fminf(fminf(r1, r2), r3);
    o.radius = max(2, (int)floorf(r));
    o.sigma = (2.0f * (float)o.radius + 1.0f) / 6.0f;
    return o;
}

// Kernel A: blocks 0..31 do rank + anno/ind/mask + packed param records
// (hidden under the fill); blocks 32..2079 zero the 83 MB heatmap with
// full-occupancy streaming stores (8 VGPR, no LDS on that path).
__global__ __launch_bounds__(256) void prep_zero_kernel(
        const float* __restrict__ boxes, const int* __restrict__ labels,
        float* __restrict__ out, int4* __restrict__ wsPar) {
    int blk = blockIdx.x;
    int tid = threadIdx.x;

    if (blk < PREP_BLKS) {
        int b = blk >> 1;
        int half = blk & 1;
        __shared__ int lab[N_];
        for (int k = tid; k < N_; k += 256) lab[k] = labels[b * N_ + k];
        __syncthreads();
        int i = half * 250 + tid;
        if (tid < 250) {
            // stable rank: #(lab[j] < c) + #(j < i: lab[j] == c)
            int c = lab[i];
            int rank = 0;
            #pragma unroll 8
            for (int j = 0; j < N_; ++j) {
                int lj = lab[j];
                rank += (lj < c) | ((lj == c) & (j < i));
            }
            const float* bx = boxes + (long)(b * N_ + i) * 9;
            ObjParams o = compute_params(bx);

            // packed record for the scatter kernel (slot = rank: a permutation,
            // every slot written exactly once; order irrelevant, max commutes)
            int4 rec;
            rec.x = o.cx;
            rec.y = o.cy;
            rec.z = o.valid ? ((min(o.radius, RMAXC) << 8) | (c - 1)) : -1;
            rec.w = __float_as_int(1.0f / (2.0f * (o.sigma * o.sigma)));
            wsPar[b * N_ + rank] = rec;

            float* anno = out + ANNO_OFF + (long)(b * N_ + rank) * 8;
            if (o.valid) {
                float zz = bx[2], w = bx[3], l = bx[4], h = bx[5], rot = bx[8];
                float4 a0 = {o.cx_f - (float)o.cx, o.cy_f - (float)o.cy, zz, logf(w)};
                float4 a1 = {logf(l), logf(h), sinf(rot), cosf(rot)};
                *(float4*)anno = a0;
                *(float4*)(anno + 4) = a1;
                out[IND_OFF + b * N_ + rank]  = (float)(o.cy * FM_ + o.cx);
                out[MASK_OFF + b * N_ + rank] = 1.0f;
            } else {
                float4 z = {0.f, 0.f, 0.f, 0.f};
                *(float4*)anno = z;
                *(float4*)(anno + 4) = z;
                out[IND_OFF + b * N_ + rank]  = 0.0f;
                out[MASK_OFF + b * N_ + rank] = 0.0f;
            }
        }
    } else {
        int zblk = blk - PREP_BLKS;
        float4* hm4 = (float4*)out;
        constexpr int n4 = (int)(HM_ELEMS / 4);
        float4 z = {0.f, 0.f, 0.f, 0.f};
        for (int k = zblk * 256 + tid; k < n4; k += ZERO_BLKS * 256) hm4[k] = z;
    }
}

// Kernel B: one wave per object. Params precomputed -> per wave: one broadcast
// int4 load + ~2-3 trips over the window; exp + fire-and-forget atomicMax
// (no return value -> no latency exposure). Kernel boundary orders vs zeros.
__global__ __launch_bounds__(256) void scatter_kernel(
        const int4* __restrict__ wsPar, float* __restrict__ out) {
    int w = blockIdx.x * 4 + (threadIdx.x >> 6);     // 0 .. B*N-1
    int lane = threadIdx.x & 63;
    int4 r = wsPar[w];
    if (r.z < 0) return;                             // invalid object
    int re  = r.z >> 8;
    int cls = r.z & 0xff;
    int cx = r.x, cy = r.y;
    float inv = __int_as_float(r.w);
    int b = w / N_;
    int wsz = 2 * re + 1;                            // <= 25
    int shift = (wsz <= 16) ? 4 : 5;                 // wave-uniform
    int cells = wsz << shift;
    float* hm = out + ((long)(b * NC + cls)) * FM_ * FM_;
    for (int cell = lane; cell < cells; cell += 64) {
        int row = cell >> shift;
        int col = cell & ((1 << shift) - 1);
        if (col >= wsz) continue;
        int dy = row - re, dx = col - re;
        int y = cy + dy, x = cx + dx;
        if (y < 0 || y >= FM_ || x < 0 || x >= FM_) continue;
        float g = expf(-(float)(dx * dx + dy * dy) * inv);
        // g >= 0, heatmap zeroed: int-view atomicMax == float max
        atomicMax((int*)&hm[y * FM_ + x], __float_as_int(g));
    }
}

extern "C" void kernel_launch(void* const* d_in, const int* in_sizes, int n_in,
                              void* d_out, int out_size, void* d_ws, size_t ws_size,
                              hipStream_t stream) {
    const float* boxes = (const float*)d_in[0];
    const int* labels  = (const int*)d_in[1];
    float* out = (float*)d_out;
    int4* wsPar = (int4*)d_ws;                       // 16*500*16 = 128 KB scratch

    prep_zero_kernel<<<PREP_BLKS + ZERO_BLKS, 256, 0, stream>>>(
        boxes, labels, out, wsPar);
    scatter_kernel<<<(B_ * N_) / 4, 256, 0, stream>>>(wsPar, out);
}